// Round 3
// baseline (816.381 us; speedup 1.0000x reference)
//
#include <hip/hip_runtime.h>

// MixtralSparseMoeBlock on gfx950.
// Inputs (fp32): hidden_states [2,2048,1024], gate_w [1024,8],
//                w1 [8,1024,3584], w3 [8,1024,3584], w2 [8,3584,1024]
// Output (fp32): final_hidden [2,2048,1024] ++ router_logits [2,2048,8]
//
// Sparse top-2: router -> per-expert gather -> bf16 MFMA GEMMs
// (32x32x16 mfma, 128x128xBK32 tiles, global_load_lds staging,
//  XOR phase swizzle) -> weighted combine.

typedef __bf16 v8bf  __attribute__((ext_vector_type(8)));
typedef float  v16f  __attribute__((ext_vector_type(16)));

constexpr int kT = 4096;   // tokens = B*S
constexpr int kH = 1024;
constexpr int kI = 3584;
constexpr int kE = 8;

// ---- workspace layout (bytes); ~252 MB. BUF aliases W1T (disjoint lifetime:
// w1t consumed by gemm1, buf produced by gemm2 afterwards in stream order).
constexpr size_t SZ_W    = (size_t)kE * kI * kH * 2;          // one bf16 weight set
constexpr size_t OFF_W1T = 0;                                  // [E][I][H] bf16
constexpr size_t OFF_W3T = OFF_W1T + SZ_W;                     // [E][I][H] bf16
constexpr size_t OFF_W2T = OFF_W3T + SZ_W;                     // [E][H][I] bf16
constexpr size_t OFF_XG  = OFF_W2T + SZ_W;                     // [2T][H] bf16 gathered tokens
constexpr size_t OFF_ACT = OFF_XG  + (size_t)2*kT*kH*2;        // [2T][I] bf16 silu(h1)*h3
constexpr size_t OFF_BUF = OFF_W1T;                            // [2T][H] f32 (alias W1T)
constexpr size_t OFF_CNT = OFF_ACT + (size_t)2*kT*kI*2;        // int[8] counts
constexpr size_t OFF_OFS = OFF_CNT + 128;                      // int[8] offsets
constexpr size_t OFF_LST = OFF_OFS + 128;                      // int[E][T] token list (t*2+k)
constexpr size_t OFF_TW  = OFF_LST + (size_t)kE*kT*4;          // float[T][2] routing weights
constexpr size_t OFF_TR  = OFF_TW  + (size_t)kT*2*4;           // int[T][2] token -> global row

__device__ __forceinline__ void async16(void* lds, const void* g) {
    __builtin_amdgcn_global_load_lds(
        (const __attribute__((address_space(1))) unsigned int*)g,
        (__attribute__((address_space(3))) unsigned int*)lds,
        16, 0, 0);
}

// ---------------------------------------------------------------- utility
__global__ void zero_counts_kernel(int* __restrict__ counts) {
    if (threadIdx.x < kE) counts[threadIdx.x] = 0;
}

__global__ void prefix_kernel(const int* __restrict__ counts, int* __restrict__ offsets) {
    if (threadIdx.x == 0) {
        int o = 0;
        for (int e = 0; e < kE; e++) { offsets[e] = o; o += counts[e]; }
    }
}

// ---------------------------------------------------------------- router
// one wave per token; fp64 accumulation so top-2 selection is stable vs np ref
__global__ void router_kernel(const float* __restrict__ x, const float* __restrict__ gw,
                              float* __restrict__ logits_out, float* __restrict__ tw,
                              int* __restrict__ counts, int* __restrict__ list) {
    const int wave = threadIdx.x >> 6;
    const int lane = threadIdx.x & 63;
    const int t = blockIdx.x * 4 + wave;
    const float* xr = x + (size_t)t * kH;

    double acc[kE];
#pragma unroll
    for (int e = 0; e < kE; e++) acc[e] = 0.0;

    for (int j = 0; j < kH / 64; j++) {
        const int h = j * 64 + lane;
        const float xv = xr[h];
        const float* g = gw + (size_t)h * kE;
#pragma unroll
        for (int e = 0; e < kE; e++) acc[e] += (double)xv * (double)g[e];
    }
#pragma unroll
    for (int e = 0; e < kE; e++) {
#pragma unroll
        for (int o = 32; o > 0; o >>= 1) acc[e] += __shfl_xor(acc[e], o, 64);
    }

    if (lane == 0) {
        float lg[kE];
#pragma unroll
        for (int e = 0; e < kE; e++) lg[e] = (float)acc[e];
#pragma unroll
        for (int e = 0; e < kE; e++) logits_out[(size_t)t * kE + e] = lg[e];

        // top-2, first-index-wins on ties (np/jax semantics)
        int e0 = 0; float l0 = lg[0];
        for (int e = 1; e < kE; e++) if (lg[e] > l0) { l0 = lg[e]; e0 = e; }
        int e1 = -1; float l1 = -3.4e38f;
        for (int e = 0; e < kE; e++) if (e != e0 && lg[e] > l1) { l1 = lg[e]; e1 = e; }

        const float ex = __expf(l1 - l0);       // l1 <= l0
        const float w0 = 1.0f / (1.0f + ex);
        const float w1 = ex / (1.0f + ex);

        int s0 = atomicAdd(&counts[e0], 1);
        list[e0 * kT + s0] = t * 2 + 0;
        tw[t * 2 + 0] = w0;
        int s1 = atomicAdd(&counts[e1], 1);
        list[e1 * kT + s1] = t * 2 + 1;
        tw[t * 2 + 1] = w1;
    }
}

// ---------------------------------------------------------------- gather
// one block per global row (exactly 2T rows total)
__global__ void gather_kernel(const float* __restrict__ x, const int* __restrict__ list,
                              const int* __restrict__ counts, const int* __restrict__ offsets,
                              __bf16* __restrict__ xg, int* __restrict__ trow) {
    const int g = blockIdx.x;                 // 0..2T-1
    int e = 0;
    while (e < kE - 1 && g >= offsets[e] + counts[e]) e++;
    const int s = g - offsets[e];
    const int entry = list[e * kT + s];
    const int t = entry >> 1;
    if (threadIdx.x == 0) trow[entry] = g;
    const int i = threadIdx.x * 4;
    const float4 v = *(const float4*)&x[(size_t)t * kH + i];
    __bf16 pk[4] = {(__bf16)v.x, (__bf16)v.y, (__bf16)v.z, (__bf16)v.w};
    *(ushort4*)&xg[(size_t)g * kH + i] = *(const ushort4*)pk;
}

// ---------------------------------------------------------------- weight transpose + cvt
// One launch for all 3 weight tensors. fp32 [R][C] -> bf16 [C][R], 64x64 tiles.
// z in [0,8): w1 expert z ; [8,16): w3 ; [16,24): w2.
__global__ void transpose_cvt_all_kernel(const float* __restrict__ w1, const float* __restrict__ w3,
                                         const float* __restrict__ w2,
                                         __bf16* __restrict__ w1t, __bf16* __restrict__ w3t,
                                         __bf16* __restrict__ w2t) {
    __shared__ float tile[64][65];
    const int z = blockIdx.z;
    const float* s; __bf16* d; int R, C;
    if (z < 8)       { s = w1 + (size_t)z * kH * kI;        d = w1t + (size_t)z * kH * kI;        R = kH; C = kI; }
    else if (z < 16) { s = w3 + (size_t)(z - 8) * kH * kI;  d = w3t + (size_t)(z - 8) * kH * kI;  R = kH; C = kI; }
    else             { s = w2 + (size_t)(z - 16) * kI * kH; d = w2t + (size_t)(z - 16) * kI * kH; R = kI; C = kH; }
    const int ntx = C / 64;                   // tiles along C
    const int tx = blockIdx.x % ntx, ty = blockIdx.x / ntx;
    const int r0 = ty * 64, c0 = tx * 64;
    const int tr = threadIdx.x >> 4;          // 0..15
    const int tc = (threadIdx.x & 15) * 4;    // 0,4,..,60
#pragma unroll
    for (int i = 0; i < 4; i++) {
        const float4 v = *(const float4*)&s[(size_t)(r0 + tr + i * 16) * C + (c0 + tc)];
        tile[tr + i * 16][tc + 0] = v.x;
        tile[tr + i * 16][tc + 1] = v.y;
        tile[tr + i * 16][tc + 2] = v.z;
        tile[tr + i * 16][tc + 3] = v.w;
    }
    __syncthreads();
#pragma unroll
    for (int i = 0; i < 4; i++) {
        const int oc = tr + i * 16;           // src col within tile = dst row
        __bf16 pk[4] = {(__bf16)tile[tc + 0][oc], (__bf16)tile[tc + 1][oc],
                        (__bf16)tile[tc + 2][oc], (__bf16)tile[tc + 3][oc]};
        *(ushort4*)&d[(size_t)(c0 + oc) * R + r0 + tc] = *(const ushort4*)pk;
    }
}

// ---------------------------------------------------------------- GEMM1 (dual-B, fused silu*mul)
// C1 = Xg @ W1t, C3 = Xg @ W3t ; act = bf16(silu(C1)*C3)
// mfma_f32_32x32x16_bf16; LDS rows of 32 elem (4 phases of 16B); slot phase s
// at row r holds global phase s ^ (r&3)  (bank-balances the 32x32 frag reads).
__global__ __launch_bounds__(256, 2) void gemm1_kernel(
    const __bf16* __restrict__ xg, const __bf16* __restrict__ w1t,
    const __bf16* __restrict__ w3t, __bf16* __restrict__ act,
    const int* __restrict__ counts, const int* __restrict__ offsets) {
    const int e = blockIdx.z;
    const int cnt = counts[e];
    const int m0 = blockIdx.y * 128;
    if (m0 >= cnt) return;
    const int n0 = blockIdx.x * 128;
    const int off = offsets[e];

    __shared__ __bf16 As[128 * 32], B1s[128 * 32], B3s[128 * 32];

    const int tid = threadIdx.x;
    const int lane = tid & 63, wave = tid >> 6;
    const int wm = (wave >> 1) * 64, wn = (wave & 1) * 64;
    const int l31 = lane & 31;
    const int half = lane >> 5;               // 0/1: k-phase within a k-step

    // staging: thread fills LDS slot (row=tid>>2, phase=tid&3) -> fetch global
    // phase (tid&3) ^ ((tid>>2)&3)
    const int scol = ((tid & 3) ^ ((tid >> 2) & 3)) * 8;
    const __bf16* abase[2];
    const __bf16* b1base[2];
    const __bf16* b3base[2];
    const __bf16* w1b = w1t + (size_t)e * kI * kH + (size_t)n0 * kH;
    const __bf16* w3b = w3t + (size_t)e * kI * kH + (size_t)n0 * kH;
#pragma unroll
    for (int p = 0; p < 2; p++) {
        const int r = p * 64 + (tid >> 2);
        const int gr = min(m0 + r, cnt - 1);           // clamp for partial tiles
        abase[p]  = xg + (size_t)(off + gr) * kH + scol;
        b1base[p] = w1b + (size_t)r * kH + scol;
        b3base[p] = w3b + (size_t)r * kH + scol;
    }

    // fragment reads: global phase g = half + 2*kstep, slot phase = g ^ (lane&3)
    const int ph0 = (half ^ (lane & 3)) * 8;          // kstep 0, element offset
    const int ph1 = ((half ^ 2) ^ (lane & 3)) * 8;    // kstep 1

    v16f acc1[2][2], acc3[2][2];
#pragma unroll
    for (int i = 0; i < 2; i++)
#pragma unroll
        for (int j = 0; j < 2; j++) { acc1[i][j] = (v16f)0.0f; acc3[i][j] = (v16f)0.0f; }

    for (int kt = 0; kt < kH / 32; kt++) {
        const int k0 = kt * 32;
#pragma unroll
        for (int p = 0; p < 2; p++) {
            const int soff = p * 2048 + tid * 8;       // elements
            async16(&As[soff],  abase[p]  + k0);
            async16(&B1s[soff], b1base[p] + k0);
            async16(&B3s[soff], b3base[p] + k0);
        }
        __syncthreads();

#pragma unroll
        for (int ks = 0; ks < 2; ks++) {
            const int ph = ks ? ph1 : ph0;
            v8bf a[2], b1[2], b3[2];
#pragma unroll
            for (int f = 0; f < 2; f++) {
                a[f]  = *(const v8bf*)&As [(wm + f * 32 + l31) * 32 + ph];
                b1[f] = *(const v8bf*)&B1s[(wn + f * 32 + l31) * 32 + ph];
                b3[f] = *(const v8bf*)&B3s[(wn + f * 32 + l31) * 32 + ph];
            }
#pragma unroll
            for (int fn = 0; fn < 2; fn++)
#pragma unroll
                for (int fm = 0; fm < 2; fm++) {
                    acc1[fm][fn] = __builtin_amdgcn_mfma_f32_32x32x16_bf16(a[fm], b1[fn], acc1[fm][fn], 0, 0, 0);
                    acc3[fm][fn] = __builtin_amdgcn_mfma_f32_32x32x16_bf16(a[fm], b3[fn], acc3[fm][fn], 0, 0, 0);
                }
        }
        __syncthreads();
    }

    // epilogue: silu(c1)*c3 -> bf16 act
    // C/D 32x32 layout: col=lane&31, row=(reg&3)+8*(reg>>2)+4*(lane>>5)
#pragma unroll
    for (int fm = 0; fm < 2; fm++) {
#pragma unroll
        for (int fn = 0; fn < 2; fn++) {
            const v16f c1 = acc1[fm][fn], c3 = acc3[fm][fn];
            const int col = n0 + wn + fn * 32 + l31;
#pragma unroll
            for (int reg = 0; reg < 16; reg++) {
                const int rloc = (reg & 3) + 8 * (reg >> 2) + 4 * half;
                const int gm = m0 + wm + fm * 32 + rloc;
                if (gm < cnt) {
                    const float h1 = c1[reg], h3 = c3[reg];
                    const float v = h1 / (1.0f + __expf(-h1)) * h3;
                    act[(size_t)(off + gm) * kI + col] = (__bf16)v;
                }
            }
        }
    }
}

// ---------------------------------------------------------------- GEMM2
// buf = act @ W2t ; same structure as gemm1, single B
__global__ __launch_bounds__(256, 2) void gemm2_kernel(
    const __bf16* __restrict__ act, const __bf16* __restrict__ w2t,
    float* __restrict__ buf,
    const int* __restrict__ counts, const int* __restrict__ offsets) {
    const int e = blockIdx.z;
    const int cnt = counts[e];
    const int m0 = blockIdx.y * 128;
    if (m0 >= cnt) return;
    const int n0 = blockIdx.x * 128;
    const int off = offsets[e];

    __shared__ __bf16 As[128 * 32], Bs[128 * 32];

    const int tid = threadIdx.x;
    const int lane = tid & 63, wave = tid >> 6;
    const int wm = (wave >> 1) * 64, wn = (wave & 1) * 64;
    const int l31 = lane & 31;
    const int half = lane >> 5;

    const int scol = ((tid & 3) ^ ((tid >> 2) & 3)) * 8;
    const __bf16* abase[2];
    const __bf16* bbase[2];
    const __bf16* w2b = w2t + (size_t)e * kH * kI + (size_t)n0 * kI;
#pragma unroll
    for (int p = 0; p < 2; p++) {
        const int r = p * 64 + (tid >> 2);
        const int gr = min(m0 + r, cnt - 1);
        abase[p] = act + (size_t)(off + gr) * kI + scol;
        bbase[p] = w2b + (size_t)r * kI + scol;
    }

    const int ph0 = (half ^ (lane & 3)) * 8;
    const int ph1 = ((half ^ 2) ^ (lane & 3)) * 8;

    v16f acc[2][2];
#pragma unroll
    for (int i = 0; i < 2; i++)
#pragma unroll
        for (int j = 0; j < 2; j++) acc[i][j] = (v16f)0.0f;

    for (int kt = 0; kt < kI / 32; kt++) {
        const int k0 = kt * 32;
#pragma unroll
        for (int p = 0; p < 2; p++) {
            const int soff = p * 2048 + tid * 8;
            async16(&As[soff], abase[p] + k0);
            async16(&Bs[soff], bbase[p] + k0);
        }
        __syncthreads();

#pragma unroll
        for (int ks = 0; ks < 2; ks++) {
            const int ph = ks ? ph1 : ph0;
            v8bf a[2], b[2];
#pragma unroll
            for (int f = 0; f < 2; f++) {
                a[f] = *(const v8bf*)&As[(wm + f * 32 + l31) * 32 + ph];
                b[f] = *(const v8bf*)&Bs[(wn + f * 32 + l31) * 32 + ph];
            }
#pragma unroll
            for (int fn = 0; fn < 2; fn++)
#pragma unroll
                for (int fm = 0; fm < 2; fm++)
                    acc[fm][fn] = __builtin_amdgcn_mfma_f32_32x32x16_bf16(a[fm], b[fn], acc[fm][fn], 0, 0, 0);
        }
        __syncthreads();
    }

#pragma unroll
    for (int fm = 0; fm < 2; fm++) {
#pragma unroll
        for (int fn = 0; fn < 2; fn++) {
            const v16f c = acc[fm][fn];
            const int col = n0 + wn + fn * 32 + l31;
#pragma unroll
            for (int reg = 0; reg < 16; reg++) {
                const int rloc = (reg & 3) + 8 * (reg >> 2) + 4 * half;
                const int gm = m0 + wm + fm * 32 + rloc;
                if (gm < cnt) buf[(size_t)(off + gm) * kH + col] = c[reg];
            }
        }
    }
}

// ---------------------------------------------------------------- combine
__global__ void combine_kernel(const float* __restrict__ buf, const int* __restrict__ trow,
                               const float* __restrict__ tw, float* __restrict__ out) {
    const int t = blockIdx.x;
    const int r0 = trow[2 * t], r1 = trow[2 * t + 1];
    const float w0 = tw[2 * t], w1 = tw[2 * t + 1];
    const int i = threadIdx.x * 4;
    const float4 a = *(const float4*)&buf[(size_t)r0 * kH + i];
    const float4 b = *(const float4*)&buf[(size_t)r1 * kH + i];
    float4 o;
    o.x = w0 * a.x + w1 * b.x;
    o.y = w0 * a.y + w1 * b.y;
    o.z = w0 * a.z + w1 * b.z;
    o.w = w0 * a.w + w1 * b.w;
    *(float4*)&out[(size_t)t * kH + i] = o;
}

// ---------------------------------------------------------------- launch
extern "C" void kernel_launch(void* const* d_in, const int* in_sizes, int n_in,
                              void* d_out, int out_size, void* d_ws, size_t ws_size,
                              hipStream_t stream) {
    const float* x  = (const float*)d_in[0];
    const float* gw = (const float*)d_in[1];
    const float* w1 = (const float*)d_in[2];
    const float* w3 = (const float*)d_in[3];
    const float* w2 = (const float*)d_in[4];
    float* out = (float*)d_out;
    float* logits_out = out + (size_t)kT * kH;

    char* ws = (char*)d_ws;
    __bf16* w1t   = (__bf16*)(ws + OFF_W1T);
    __bf16* w3t   = (__bf16*)(ws + OFF_W3T);
    __bf16* w2t   = (__bf16*)(ws + OFF_W2T);
    __bf16* xg    = (__bf16*)(ws + OFF_XG);
    __bf16* act   = (__bf16*)(ws + OFF_ACT);
    float*  buf   = (float*) (ws + OFF_BUF);   // aliases W1T (disjoint lifetime)
    int*    cnt   = (int*)   (ws + OFF_CNT);
    int*    ofs   = (int*)   (ws + OFF_OFS);
    int*    list  = (int*)   (ws + OFF_LST);
    float*  tw    = (float*) (ws + OFF_TW);
    int*    trow  = (int*)   (ws + OFF_TR);

    zero_counts_kernel<<<1, 64, 0, stream>>>(cnt);

    // all three weight transposes in one launch (896 tiles per matrix, z=24)
    transpose_cvt_all_kernel<<<dim3(896, 1, 24), 256, 0, stream>>>(w1, w3, w2, w1t, w3t, w2t);

    router_kernel<<<kT / 4, 256, 0, stream>>>(x, gw, logits_out, tw, cnt, list);
    prefix_kernel<<<1, 1, 0, stream>>>(cnt, ofs);
    gather_kernel<<<2 * kT, 256, 0, stream>>>(x, list, cnt, ofs, xg, trow);

    gemm1_kernel<<<dim3(kI / 128, kT / 128, kE), 256, 0, stream>>>(xg, w1t, w3t, act, cnt, ofs);
    gemm2_kernel<<<dim3(kH / 128, kT / 128, kE), 256, 0, stream>>>(act, w2t, buf, cnt, ofs);

    combine_kernel<<<kT, 256, 0, stream>>>(buf, trow, tw, out);
}